// Round 15
// baseline (52.340 us; speedup 1.0000x reference)
//
#include <hip/hip_runtime.h>
#include <math.h>

#define EPSF 1e-7f

typedef __attribute__((ext_vector_type(4))) float f32x4;
typedef __attribute__((ext_vector_type(8))) short s16x8;

__device__ __forceinline__ unsigned short f2bf(float f) {
    unsigned u = __float_as_uint(f);
    u = (u + 0x7fffu + ((u >> 16) & 1u)) >> 16;
    return (unsigned short)u;
}
__device__ __forceinline__ s16x8 cvt8(const float* p) {
    s16x8 r;
    #pragma unroll
    for (int i = 0; i < 8; ++i) r[i] = (short)f2bf(p[i]);
    return r;
}

// K1: fused logmap + QKV GEMM + RoPE + expmap0 (R12/R14-proven) + out=bias init.
__global__ __launch_bounds__(256, 4) void k_qkv_rope(
        const float* __restrict__ x, const float* __restrict__ W,
        const float* __restrict__ bias, const float* __restrict__ c_sphere,
        const float* __restrict__ freqs, const float* __restrict__ c_logits,
        const float* __restrict__ b_out, float* __restrict__ out,
        unsigned short* __restrict__ qh, unsigned short* __restrict__ kh,
        unsigned short* __restrict__ vt,
        float* __restrict__ x2q, float* __restrict__ y2k) {
    const int K = 512, NN = 1536, N = 512;
    int b = blockIdx.x;
    int rt = b >> 3, h = b & 7;
    int n0 = rt * 16;
    int tid = threadIdx.x;
    int wv = tid >> 6, lane = tid & 63, l15 = lane & 15, kb = lane >> 4;
    __shared__ float part[16][16];
    __shared__ float sL[16];
    __shared__ float pq[16][65];
    __shared__ float pk[16][65];

    // out = bias init (rows 2b, 2b+1); overwritten every replay -> deterministic
    {
        float bv0 = b_out[tid], bv1 = b_out[tid + 256];
        out[(size_t)(2 * b) * 512 + tid] = bv0;
        out[(size_t)(2 * b) * 512 + tid + 256] = bv1;
        out[(size_t)(2 * b + 1) * 512 + tid] = bv0;
        out[(size_t)(2 * b + 1) * 512 + tid + 256] = bv1;
    }

    {   // logmap prologue
        int row = tid >> 4, seg = tid & 15;
        const float* xr = x + (size_t)(n0 + row) * K + seg * 32;
        float ss = 0.f;
        #pragma unroll
        for (int i = 0; i < 8; ++i) {
            float4 v = *(const float4*)(xr + i * 4);
            ss += v.x * v.x + v.y * v.y + v.z * v.z + v.w * v.w;
        }
        part[row][seg] = ss;
    }
    __syncthreads();
    if (tid < 16) {
        float ss = 0.f;
        #pragma unroll
        for (int i = 0; i < 16; ++i) ss += part[tid][i];
        float c = c_sphere[0];
        float sqc = fmaxf(sqrtf(c), EPSF);
        float yn = sqrtf(ss);
        sL[tid] = (yn < EPSF) ? 0.f
                 : atanhf(fminf(yn, 1.f - EPSF)) / (sqc * fmaxf(yn, EPSF));
    }
    __syncthreads();

    int cq = h * 64 + wv * 16 + l15;
    const float* Ab = x + (size_t)(n0 + l15) * K + kb * 8;
    f32x4 accq = {}, acck = {}, accv = {};
    #pragma unroll 4
    for (int k0 = 0; k0 < K; k0 += 32) {
        s16x8 a = cvt8(Ab + k0);
        s16x8 bq, bk, bv;
        #pragma unroll
        for (int t = 0; t < 8; ++t) {
            const float* wp = W + (size_t)(k0 + kb * 8 + t) * NN + cq;
            bq[t] = (short)f2bf(wp[0]);
            bk[t] = (short)f2bf(wp[512]);
            bv[t] = (short)f2bf(wp[1024]);
        }
        accq = __builtin_amdgcn_mfma_f32_16x16x32_bf16(a, bq, accq, 0, 0, 0);
        acck = __builtin_amdgcn_mfma_f32_16x16x32_bf16(a, bk, acck, 0, 0, 0);
        accv = __builtin_amdgcn_mfma_f32_16x16x32_bf16(a, bv, accv, 0, 0, 0);
    }
    {
        float bq_ = bias[cq], bk_ = bias[512 + cq], bv_ = bias[1024 + cq];
        int d = wv * 16 + l15;
        #pragma unroll
        for (int r = 0; r < 4; ++r) {
            int row_l = kb * 4 + r;
            float sc = sL[row_l];
            pq[row_l][d] = accq[r] * sc + bq_;
            pk[row_l][d] = acck[r] * sc + bk_;
            float vval = accv[r] * sc + bv_;
            vt[((size_t)(h * 64 + d)) * N + n0 + row_l] = f2bf(vval);
        }
    }
    __syncthreads();

    // RoPE + expmap: 4 vectors per wave in parallel (16-lane groups).
    int row_l = wv * 4 + kb;
    int n = n0 + row_l;
    float c = log1pf(expf(c_logits[h]));
    float sqc = fmaxf(sqrtf(c), EPSF);
    float f1 = freqs[n * 32 + l15];
    float f2 = freqs[n * 32 + l15 + 16];
    float c1 = cosf(f1), s1 = sinf(f1), c2 = cosf(f2), s2 = sinf(f2);
    size_t obase = ((size_t)h * N + n) * 64;
    #pragma unroll
    for (int qk = 0; qk < 2; ++qk) {
        const float (*P)[65] = qk ? pk : pq;
        float a1 = P[row_l][l15],      b1 = P[row_l][l15 + 32];
        float a2 = P[row_l][l15 + 16], b2 = P[row_l][l15 + 48];
        float o0 = a1 * c1 - b1 * s1;
        float o1 = a2 * c2 - b2 * s2;
        float o2 = a1 * s1 + b1 * c1;
        float o3 = a2 * s2 + b2 * c2;
        float loc = o0 * o0 + o1 * o1 + o2 * o2 + o3 * o3;
        #pragma unroll
        for (int xo = 1; xo < 16; xo <<= 1) loc += __shfl_xor(loc, xo, 64);
        float vn = sqrtf(loc);
        float scale, fn;
        if (vn < EPSF) { scale = 0.f; fn = 0.f; }
        else {
            float mag = tanhf(sqc * vn) / sqc;
            scale = mag / fmaxf(vn, EPSF);
            fn = mag;
            if (fn >= 1.f) { scale *= (1.f - EPSF) / fn; fn = 1.f - EPSF; }
        }
        unsigned short* outp = (qk ? kh : qh) + obase;
        outp[l15]      = f2bf(o0 * scale);
        outp[l15 + 16] = f2bf(o1 * scale);
        outp[l15 + 32] = f2bf(o2 * scale);
        outp[l15 + 48] = f2bf(o3 * scale);
        if (l15 == 0) (qk ? y2k : x2q)[h * N + n] = fn * fn;
    }
}

// K2: fused attention + out-projection.
// Phase 1: QK^T + dist/exp -> LDS P tile (zero-padded to even 16-tiles).
// Phase 2: O = P@V + ones-MFMA row-sum.
// Phase 3: normalized O (bf16, LDS) @ W_out[h*64.., :] -> 16x512 partial,
//          atomicAdd into bias-initialized out (linear in heads).
__global__ __launch_bounds__(256, 4) void k_attn(
        const unsigned short* __restrict__ qh, const unsigned short* __restrict__ kh,
        const unsigned short* __restrict__ vt,
        const float* __restrict__ x2q, const float* __restrict__ y2k,
        const float* __restrict__ c_logits, const float* __restrict__ geo_scale,
        const float* __restrict__ W_out, float* __restrict__ out) {
    const int N = 512;
    int rt = blockIdx.x, h = blockIdx.y;
    int r0 = rt * 16;
    int kend = r0 + 16;
    int tid = threadIdx.x;
    int wv = tid >> 6, lane = tid & 63, l15 = lane & 15, kb = lane >> 4;
    __shared__ __align__(16) unsigned short Ps[16][520];   // stride 1040B

    float c = log1pf(expf(c_logits[h]));
    float sqc = fmaxf(sqrtf(c), EPSF);
    float gs = geo_scale[h];

    // ---- Phase 1 ----
    const unsigned short* qb = qh + ((size_t)h * N + r0 + l15) * 64 + kb * 8;
    s16x8 aq0 = *(const s16x8*)(qb);
    s16x8 aq1 = *(const s16x8*)(qb + 32);
    float x2v[4], bv[4];
    #pragma unroll
    for (int r = 0; r < 4; ++r) {
        int qi = r0 + kb * 4 + r;
        x2v[r] = x2q[h * N + qi];
        bv[r] = 1.f - c * x2v[r];
    }
    int ntile = rt + 1;
    int ntile_pad = (ntile + 1) & ~1;
    for (int j = wv; j < ntile_pad; j += 4) {
        if (j < ntile) {
            const unsigned short* kbp = kh + ((size_t)h * N + j * 16 + l15) * 64 + kb * 8;
            f32x4 s = {};
            s = __builtin_amdgcn_mfma_f32_16x16x32_bf16(aq0, *(const s16x8*)(kbp), s, 0, 0, 0);
            s = __builtin_amdgcn_mfma_f32_16x16x32_bf16(aq1, *(const s16x8*)(kbp + 32), s, 0, 0, 0);
            int ki = j * 16 + l15;
            float y2 = y2k[h * N + ki];
            #pragma unroll
            for (int r = 0; r < 4; ++r) {
                int qi = r0 + kb * 4 + r;
                float dot = s[r];
                float x2 = x2v[r], b_ = bv[r];
                float a_ = 1.f + c * (y2 - 2.f * dot);
                float num2 = a_ * a_ * x2 + b_ * b_ * y2 - 2.f * a_ * b_ * dot;
                float den = fmaxf(1.f - 2.f * c * dot + c * c * x2 * y2, EPSF);
                float nrm = sqrtf(fmaxf(num2, 0.f)) / den;
                if (nrm >= 1.f) nrm = 1.f - EPSF;
                float arg = fminf(sqc * nrm, 1.f - EPSF);
                float sv = -gs * (2.f * atanhf(arg) / sqc);
                float pe = (ki <= qi) ? expf(sv) : 0.f;
                Ps[kb * 4 + r][j * 16 + l15] = f2bf(pe);
            }
        } else {
            #pragma unroll
            for (int r = 0; r < 4; ++r)
                Ps[kb * 4 + r][j * 16 + l15] = 0;
        }
    }
    __syncthreads();

    // ---- Phase 2: O = P@V + ones-MFMA row-sum ----
    s16x8 ones;
    #pragma unroll
    for (int i = 0; i < 8; ++i) ones[i] = (short)0x3F80;   // bf16 1.0
    int d0 = wv * 16;
    const unsigned short* Vb = vt + ((size_t)(h * 64 + d0 + l15)) * N + kb * 8;
    f32x4 acc = {};
    f32x4 acc_s = {};
    for (int k0 = 0; k0 < kend; k0 += 32) {
        s16x8 a = *(const s16x8*)(&Ps[l15][k0 + kb * 8]);
        s16x8 b = *(const s16x8*)(Vb + k0);
        acc = __builtin_amdgcn_mfma_f32_16x16x32_bf16(a, b, acc, 0, 0, 0);
        acc_s = __builtin_amdgcn_mfma_f32_16x16x32_bf16(a, ones, acc_s, 0, 0, 0);
    }
    __syncthreads();   // all Ps reads done -> safe to reuse as Os

    // ---- Phase 3: out-proj partial + atomicAdd ----
    unsigned short (*Os)[72] = reinterpret_cast<unsigned short (*)[72]>(&Ps[0][0]);
    #pragma unroll
    for (int r = 0; r < 4; ++r) {
        int row_l = kb * 4 + r;
        float il = 1.f / acc_s[r];
        Os[row_l][d0 + l15] = f2bf(acc[r] * il);
    }
    __syncthreads();
    s16x8 aO0 = *(const s16x8*)(&Os[l15][kb * 8]);
    s16x8 aO1 = *(const s16x8*)(&Os[l15][32 + kb * 8]);
    #pragma unroll 2
    for (int g = 0; g < 8; ++g) {
        int col0 = wv * 16 + g * 64;
        s16x8 b0, b1;
        #pragma unroll
        for (int t = 0; t < 8; ++t) {
            const float* wp = W_out + (size_t)(h * 64 + kb * 8 + t) * 512 + col0 + l15;
            b0[t] = (short)f2bf(wp[0]);
            b1[t] = (short)f2bf(wp[32 * 512]);
        }
        f32x4 o = {};
        o = __builtin_amdgcn_mfma_f32_16x16x32_bf16(aO0, b0, o, 0, 0, 0);
        o = __builtin_amdgcn_mfma_f32_16x16x32_bf16(aO1, b1, o, 0, 0, 0);
        #pragma unroll
        for (int r = 0; r < 4; ++r)
            atomicAdd(&out[(size_t)(r0 + kb * 4 + r) * 512 + col0 + l15], o[r]);
    }
}

extern "C" void kernel_launch(void* const* d_in, const int* in_sizes, int n_in,
                              void* d_out, int out_size, void* d_ws, size_t ws_size,
                              hipStream_t stream) {
    const float* x_hyp     = (const float*)d_in[0];
    const float* freqs     = (const float*)d_in[1];
    const float* c_sphere  = (const float*)d_in[2];
    const float* w_qkv     = (const float*)d_in[3];
    const float* b_qkv     = (const float*)d_in[4];
    const float* w_out     = (const float*)d_in[5];
    const float* b_out     = (const float*)d_in[6];
    const float* c_logits  = (const float*)d_in[7];
    const float* geo_scale = (const float*)d_in[8];
    float* out = (float*)d_out;

    const int H = 8;
    char* base = (char*)d_ws;
    unsigned short* qh16   = (unsigned short*)base;    base += 512 * 1024;
    unsigned short* kh16   = (unsigned short*)base;    base += 512 * 1024;
    unsigned short* vt16   = (unsigned short*)base;    base += 512 * 1024;
    float*          x2q    = (float*)base;             base += 16 * 1024;
    float*          y2k    = (float*)base;             base += 16 * 1024;

    k_qkv_rope<<<256, 256, 0, stream>>>(x_hyp, w_qkv, b_qkv, c_sphere, freqs,
                                        c_logits, b_out, out,
                                        qh16, kh16, vt16, x2q, y2k);
    k_attn<<<dim3(32, H), 256, 0, stream>>>(qh16, kh16, vt16, x2q, y2k,
                                            c_logits, geo_scale, w_out, out);
}

// Round 16
// 42.377 us; speedup vs baseline: 1.2351x; 1.2351x over previous
//
#include <hip/hip_runtime.h>
#include <math.h>

#define EPSF 1e-7f

typedef __attribute__((ext_vector_type(4))) float f32x4;
typedef __attribute__((ext_vector_type(8))) short s16x8;

__device__ __forceinline__ unsigned short f2bf(float f) {
    unsigned u = __float_as_uint(f);
    u = (u + 0x7fffu + ((u >> 16) & 1u)) >> 16;
    return (unsigned short)u;
}
__device__ __forceinline__ s16x8 cvt8(const float* p) {
    s16x8 r;
    #pragma unroll
    for (int i = 0; i < 8; ++i) r[i] = (short)f2bf(p[i]);
    return r;
}

// K1: fused logmap + QKV GEMM + RoPE + expmap0 (R12/R14-proven).
__global__ __launch_bounds__(256, 4) void k_qkv_rope(
        const float* __restrict__ x, const float* __restrict__ W,
        const float* __restrict__ bias, const float* __restrict__ c_sphere,
        const float* __restrict__ freqs, const float* __restrict__ c_logits,
        unsigned short* __restrict__ qh, unsigned short* __restrict__ kh,
        unsigned short* __restrict__ vt,
        float* __restrict__ x2q, float* __restrict__ y2k) {
    const int K = 512, NN = 1536, N = 512;
    int b = blockIdx.x;
    int rt = b >> 3, h = b & 7;
    int n0 = rt * 16;
    int tid = threadIdx.x;
    int wv = tid >> 6, lane = tid & 63, l15 = lane & 15, kb = lane >> 4;
    __shared__ float part[16][16];
    __shared__ float sL[16];
    __shared__ float pq[16][65];
    __shared__ float pk[16][65];

    {   // logmap prologue
        int row = tid >> 4, seg = tid & 15;
        const float* xr = x + (size_t)(n0 + row) * K + seg * 32;
        float ss = 0.f;
        #pragma unroll
        for (int i = 0; i < 8; ++i) {
            float4 v = *(const float4*)(xr + i * 4);
            ss += v.x * v.x + v.y * v.y + v.z * v.z + v.w * v.w;
        }
        part[row][seg] = ss;
    }
    __syncthreads();
    if (tid < 16) {
        float ss = 0.f;
        #pragma unroll
        for (int i = 0; i < 16; ++i) ss += part[tid][i];
        float c = c_sphere[0];
        float sqc = fmaxf(sqrtf(c), EPSF);
        float yn = sqrtf(ss);
        sL[tid] = (yn < EPSF) ? 0.f
                 : atanhf(fminf(yn, 1.f - EPSF)) / (sqc * fmaxf(yn, EPSF));
    }
    __syncthreads();

    int cq = h * 64 + wv * 16 + l15;
    const float* Ab = x + (size_t)(n0 + l15) * K + kb * 8;
    f32x4 accq = {}, acck = {}, accv = {};
    #pragma unroll 4
    for (int k0 = 0; k0 < K; k0 += 32) {
        s16x8 a = cvt8(Ab + k0);
        s16x8 bq, bk, bv;
        #pragma unroll
        for (int t = 0; t < 8; ++t) {
            const float* wp = W + (size_t)(k0 + kb * 8 + t) * NN + cq;
            bq[t] = (short)f2bf(wp[0]);
            bk[t] = (short)f2bf(wp[512]);
            bv[t] = (short)f2bf(wp[1024]);
        }
        accq = __builtin_amdgcn_mfma_f32_16x16x32_bf16(a, bq, accq, 0, 0, 0);
        acck = __builtin_amdgcn_mfma_f32_16x16x32_bf16(a, bk, acck, 0, 0, 0);
        accv = __builtin_amdgcn_mfma_f32_16x16x32_bf16(a, bv, accv, 0, 0, 0);
    }
    {
        float bq_ = bias[cq], bk_ = bias[512 + cq], bv_ = bias[1024 + cq];
        int d = wv * 16 + l15;
        #pragma unroll
        for (int r = 0; r < 4; ++r) {
            int row_l = kb * 4 + r;
            float sc = sL[row_l];
            pq[row_l][d] = accq[r] * sc + bq_;
            pk[row_l][d] = acck[r] * sc + bk_;
            float vval = accv[r] * sc + bv_;
            vt[((size_t)(h * 64 + d)) * N + n0 + row_l] = f2bf(vval);
        }
    }
    __syncthreads();

    // RoPE + expmap: 4 vectors per wave in parallel (16-lane groups).
    int row_l = wv * 4 + kb;
    int n = n0 + row_l;
    float c = log1pf(expf(c_logits[h]));
    float sqc = fmaxf(sqrtf(c), EPSF);
    float f1 = freqs[n * 32 + l15];
    float f2 = freqs[n * 32 + l15 + 16];
    float c1 = cosf(f1), s1 = sinf(f1), c2 = cosf(f2), s2 = sinf(f2);
    size_t obase = ((size_t)h * N + n) * 64;
    #pragma unroll
    for (int qk = 0; qk < 2; ++qk) {
        const float (*P)[65] = qk ? pk : pq;
        float a1 = P[row_l][l15],      b1 = P[row_l][l15 + 32];
        float a2 = P[row_l][l15 + 16], b2 = P[row_l][l15 + 48];
        float o0 = a1 * c1 - b1 * s1;
        float o1 = a2 * c2 - b2 * s2;
        float o2 = a1 * s1 + b1 * c1;
        float o3 = a2 * s2 + b2 * c2;
        float loc = o0 * o0 + o1 * o1 + o2 * o2 + o3 * o3;
        #pragma unroll
        for (int xo = 1; xo < 16; xo <<= 1) loc += __shfl_xor(loc, xo, 64);
        float vn = sqrtf(loc);
        float scale, fn;
        if (vn < EPSF) { scale = 0.f; fn = 0.f; }
        else {
            float mag = tanhf(sqc * vn) / sqc;
            scale = mag / fmaxf(vn, EPSF);
            fn = mag;
            if (fn >= 1.f) { scale *= (1.f - EPSF) / fn; fn = 1.f - EPSF; }
        }
        unsigned short* outp = (qk ? kh : qh) + obase;
        outp[l15]      = f2bf(o0 * scale);
        outp[l15 + 16] = f2bf(o1 * scale);
        outp[l15 + 32] = f2bf(o2 * scale);
        outp[l15 + 48] = f2bf(o3 * scale);
        if (l15 == 0) (qk ? y2k : x2q)[h * N + n] = fn * fn;
    }
}

// K2: fused attention (R14-proven structure). Epilogue optimization:
//   exp(-gs*2*atanh(z)/sqrt(c)) == ((1-z)/(1+z))^(gs/sqrt(c))
// -> one fast __logf + one fast __expf per score instead of the
// atanhf+expf libcall pair (~1M scores).
__global__ __launch_bounds__(256, 4) void k_attn(
        const unsigned short* __restrict__ qh, const unsigned short* __restrict__ kh,
        const unsigned short* __restrict__ vt,
        const float* __restrict__ x2q, const float* __restrict__ y2k,
        const float* __restrict__ c_logits, const float* __restrict__ geo_scale,
        unsigned short* __restrict__ aout) {
    const int N = 512;
    int rt = blockIdx.x, h = blockIdx.y;
    int r0 = rt * 16;
    int kend = r0 + 16;
    int tid = threadIdx.x;
    int wv = tid >> 6, lane = tid & 63, l15 = lane & 15, kb = lane >> 4;
    __shared__ __align__(16) unsigned short Ps[16][520];   // stride 1040B

    float c = log1pf(expf(c_logits[h]));
    float sqc = fmaxf(sqrtf(c), EPSF);
    float gs = geo_scale[h];
    float alpha = gs / sqc;                 // pow exponent

    // ---- Phase 1: S tiles -> dist/exp -> LDS (zero-padded to even tiles) ----
    const unsigned short* qb = qh + ((size_t)h * N + r0 + l15) * 64 + kb * 8;
    s16x8 aq0 = *(const s16x8*)(qb);
    s16x8 aq1 = *(const s16x8*)(qb + 32);
    float x2v[4], bv[4];
    #pragma unroll
    for (int r = 0; r < 4; ++r) {
        int qi = r0 + kb * 4 + r;
        x2v[r] = x2q[h * N + qi];
        bv[r] = 1.f - c * x2v[r];
    }
    int ntile = rt + 1;
    int ntile_pad = (ntile + 1) & ~1;      // even # of 16-col tiles
    for (int j = wv; j < ntile_pad; j += 4) {
        if (j < ntile) {
            const unsigned short* kbp = kh + ((size_t)h * N + j * 16 + l15) * 64 + kb * 8;
            f32x4 s = {};
            s = __builtin_amdgcn_mfma_f32_16x16x32_bf16(aq0, *(const s16x8*)(kbp), s, 0, 0, 0);
            s = __builtin_amdgcn_mfma_f32_16x16x32_bf16(aq1, *(const s16x8*)(kbp + 32), s, 0, 0, 0);
            int ki = j * 16 + l15;
            float y2 = y2k[h * N + ki];
            #pragma unroll
            for (int r = 0; r < 4; ++r) {
                int qi = r0 + kb * 4 + r;
                float dot = s[r];
                float x2 = x2v[r], b_ = bv[r];
                float a_ = 1.f + c * (y2 - 2.f * dot);
                float num2 = a_ * a_ * x2 + b_ * b_ * y2 - 2.f * a_ * b_ * dot;
                float den = fmaxf(1.f - 2.f * c * dot + c * c * x2 * y2, EPSF);
                float nrm = sqrtf(fmaxf(num2, 0.f)) / den;
                if (nrm >= 1.f) nrm = 1.f - EPSF;
                float arg = fminf(sqc * nrm, 1.f - EPSF);
                // pe = ((1-arg)/(1+arg))^alpha
                float ratio = (1.f - arg) / (1.f + arg);
                float pe = __expf(alpha * __logf(ratio));
                pe = (ki <= qi) ? pe : 0.f;
                Ps[kb * 4 + r][j * 16 + l15] = f2bf(pe);
            }
        } else {
            #pragma unroll
            for (int r = 0; r < 4; ++r)
                Ps[kb * 4 + r][j * 16 + l15] = 0;
        }
    }
    __syncthreads();

    // ---- Phase 2: O = P@V + ones-MFMA row-sum ----
    s16x8 ones;
    #pragma unroll
    for (int i = 0; i < 8; ++i) ones[i] = (short)0x3F80;   // bf16 1.0
    int d0 = wv * 16;
    const unsigned short* Vb = vt + ((size_t)(h * 64 + d0 + l15)) * N + kb * 8;
    f32x4 acc = {};
    f32x4 acc_s = {};
    for (int k0 = 0; k0 < kend; k0 += 32) {
        s16x8 a = *(const s16x8*)(&Ps[l15][k0 + kb * 8]);
        s16x8 b = *(const s16x8*)(Vb + k0);
        acc = __builtin_amdgcn_mfma_f32_16x16x32_bf16(a, b, acc, 0, 0, 0);
        acc_s = __builtin_amdgcn_mfma_f32_16x16x32_bf16(a, ones, acc_s, 0, 0, 0);
    }
    #pragma unroll
    for (int r = 0; r < 4; ++r) {
        int qi = r0 + kb * 4 + r;
        float il = 1.f / acc_s[r];
        aout[(size_t)qi * 512 + h * 64 + d0 + l15] = f2bf(acc[r] * il);
    }
}

// K3: out = aout(bf16) @ W_out + b. 16x16 tiles, W gathered fp32->bf16.
__global__ __launch_bounds__(256, 4) void k_out(
        const unsigned short* __restrict__ A, const float* __restrict__ W,
        const float* __restrict__ bias, float* __restrict__ C) {
    const int K = 512, NN = 512;
    int tid = threadIdx.x;
    int wv = tid >> 6, lane = tid & 63, l15 = lane & 15, kb = lane >> 4;
    int wr = blockIdx.x / 8;
    int cg = blockIdx.x % 8;
    int col0 = cg * 64 + wv * 16;
    const unsigned short* Ab = A + (size_t)(wr * 16 + l15) * K + kb * 8;
    f32x4 acc = {};
    #pragma unroll 4
    for (int k0 = 0; k0 < K; k0 += 32) {
        s16x8 a = *(const s16x8*)(Ab + k0);
        s16x8 b;
        #pragma unroll
        for (int t = 0; t < 8; ++t)
            b[t] = (short)f2bf(W[(size_t)(k0 + kb * 8 + t) * NN + col0 + l15]);
        acc = __builtin_amdgcn_mfma_f32_16x16x32_bf16(a, b, acc, 0, 0, 0);
    }
    int col = col0 + l15;
    float bv = bias[col];
    #pragma unroll
    for (int r = 0; r < 4; ++r)
        C[(size_t)(wr * 16 + kb * 4 + r) * NN + col] = acc[r] + bv;
}

extern "C" void kernel_launch(void* const* d_in, const int* in_sizes, int n_in,
                              void* d_out, int out_size, void* d_ws, size_t ws_size,
                              hipStream_t stream) {
    const float* x_hyp     = (const float*)d_in[0];
    const float* freqs     = (const float*)d_in[1];
    const float* c_sphere  = (const float*)d_in[2];
    const float* w_qkv     = (const float*)d_in[3];
    const float* b_qkv     = (const float*)d_in[4];
    const float* w_out     = (const float*)d_in[5];
    const float* b_out     = (const float*)d_in[6];
    const float* c_logits  = (const float*)d_in[7];
    const float* geo_scale = (const float*)d_in[8];
    float* out = (float*)d_out;

    const int H = 8;
    char* base = (char*)d_ws;
    unsigned short* qh16   = (unsigned short*)base;    base += 512 * 1024;
    unsigned short* kh16   = (unsigned short*)base;    base += 512 * 1024;
    unsigned short* vt16   = (unsigned short*)base;    base += 512 * 1024;
    unsigned short* aout16 = (unsigned short*)base;    base += 512 * 1024;
    float*          x2q    = (float*)base;             base += 16 * 1024;
    float*          y2k    = (float*)base;             base += 16 * 1024;

    k_qkv_rope<<<256, 256, 0, stream>>>(x_hyp, w_qkv, b_qkv, c_sphere, freqs,
                                        c_logits, qh16, kh16, vt16, x2q, y2k);
    k_attn<<<dim3(32, H), 256, 0, stream>>>(qh16, kh16, vt16, x2q, y2k,
                                            c_logits, geo_scale, aout16);
    k_out<<<256, 256, 0, stream>>>(aout16, w_out, b_out, out);
}

// Round 18
// 41.457 us; speedup vs baseline: 1.2625x; 1.0222x over previous
//
#include <hip/hip_runtime.h>
#include <math.h>

#define EPSF 1e-7f

typedef __attribute__((ext_vector_type(4))) float f32x4;
typedef __attribute__((ext_vector_type(8))) short s16x8;

__device__ __forceinline__ unsigned short f2bf(float f) {
    unsigned u = __float_as_uint(f);
    u = (u + 0x7fffu + ((u >> 16) & 1u)) >> 16;
    return (unsigned short)u;
}
__device__ __forceinline__ s16x8 cvt8(const float* p) {
    s16x8 r;
    #pragma unroll
    for (int i = 0; i < 8; ++i) r[i] = (short)f2bf(p[i]);
    return r;
}
// raw HW transcendentals (both base-2: v_exp_f32 computes 2^x, v_log_f32 log2)
__device__ __forceinline__ float exp2_hw(float x) {
    return __builtin_amdgcn_exp2f(x);
}
__device__ __forceinline__ float log2_hw(float x) {
    return __builtin_amdgcn_logf(x);
}
#define LOG2E 1.44269504088896340736f
#define LN2   0.69314718055994530942f
// fast softplus: log(1+e^x) via HW exp/log (~2 ulp; c is a smooth param)
__device__ __forceinline__ float softplus_fast(float x) {
    return LN2 * log2_hw(1.f + exp2_hw(LOG2E * x));
}
// fast tanh for x>=0: (e^2x-1)/(e^2x+1), clamped to avoid inf/inf
__device__ __forceinline__ float tanh_fast(float x) {
    float t = exp2_hw(2.f * LOG2E * fminf(x, 10.f));
    return (t - 1.f) / (t + 1.f);
}

// K1: fused logmap + QKV GEMM + RoPE + expmap0 (R12/R14 structure,
// R17: libcall-free transcendentals in the per-thread hot path).
__global__ __launch_bounds__(256, 4) void k_qkv_rope(
        const float* __restrict__ x, const float* __restrict__ W,
        const float* __restrict__ bias, const float* __restrict__ c_sphere,
        const float* __restrict__ freqs, const float* __restrict__ c_logits,
        unsigned short* __restrict__ qh, unsigned short* __restrict__ kh,
        unsigned short* __restrict__ vt,
        float* __restrict__ x2q, float* __restrict__ y2k) {
    const int K = 512, NN = 1536, N = 512;
    int b = blockIdx.x;
    int rt = b >> 3, h = b & 7;
    int n0 = rt * 16;
    int tid = threadIdx.x;
    int wv = tid >> 6, lane = tid & 63, l15 = lane & 15, kb = lane >> 4;
    __shared__ float part[16][16];
    __shared__ float sL[16];
    __shared__ float pq[16][65];
    __shared__ float pk[16][65];

    {   // logmap prologue
        int row = tid >> 4, seg = tid & 15;
        const float* xr = x + (size_t)(n0 + row) * K + seg * 32;
        float ss = 0.f;
        #pragma unroll
        for (int i = 0; i < 8; ++i) {
            float4 v = *(const float4*)(xr + i * 4);
            ss += v.x * v.x + v.y * v.y + v.z * v.z + v.w * v.w;
        }
        part[row][seg] = ss;
    }
    __syncthreads();
    if (tid < 16) {
        float ss = 0.f;
        #pragma unroll
        for (int i = 0; i < 16; ++i) ss += part[tid][i];
        float c = c_sphere[0];
        float sqc = fmaxf(sqrtf(c), EPSF);
        float yn = sqrtf(ss);
        sL[tid] = (yn < EPSF) ? 0.f
                 : atanhf(fminf(yn, 1.f - EPSF)) / (sqc * fmaxf(yn, EPSF));
    }
    __syncthreads();

    int cq = h * 64 + wv * 16 + l15;
    const float* Ab = x + (size_t)(n0 + l15) * K + kb * 8;
    f32x4 accq = {}, acck = {}, accv = {};
    #pragma unroll 4
    for (int k0 = 0; k0 < K; k0 += 32) {
        s16x8 a = cvt8(Ab + k0);
        s16x8 bq, bk, bv;
        #pragma unroll
        for (int t = 0; t < 8; ++t) {
            const float* wp = W + (size_t)(k0 + kb * 8 + t) * NN + cq;
            bq[t] = (short)f2bf(wp[0]);
            bk[t] = (short)f2bf(wp[512]);
            bv[t] = (short)f2bf(wp[1024]);
        }
        accq = __builtin_amdgcn_mfma_f32_16x16x32_bf16(a, bq, accq, 0, 0, 0);
        acck = __builtin_amdgcn_mfma_f32_16x16x32_bf16(a, bk, acck, 0, 0, 0);
        accv = __builtin_amdgcn_mfma_f32_16x16x32_bf16(a, bv, accv, 0, 0, 0);
    }
    {
        float bq_ = bias[cq], bk_ = bias[512 + cq], bv_ = bias[1024 + cq];
        int d = wv * 16 + l15;
        #pragma unroll
        for (int r = 0; r < 4; ++r) {
            int row_l = kb * 4 + r;
            float sc = sL[row_l];
            pq[row_l][d] = accq[r] * sc + bq_;
            pk[row_l][d] = acck[r] * sc + bk_;
            float vval = accv[r] * sc + bv_;
            vt[((size_t)(h * 64 + d)) * N + n0 + row_l] = f2bf(vval);
        }
    }
    __syncthreads();

    // RoPE + expmap: 4 vectors per wave in parallel (16-lane groups).
    int row_l = wv * 4 + kb;
    int n = n0 + row_l;
    float c = softplus_fast(c_logits[h]);
    float sqc = fmaxf(sqrtf(c), EPSF);
    float f1 = freqs[n * 32 + l15];
    float f2 = freqs[n * 32 + l15 + 16];
    float c1 = __cosf(f1), s1 = __sinf(f1);
    float c2 = __cosf(f2), s2 = __sinf(f2);
    size_t obase = ((size_t)h * N + n) * 64;
    #pragma unroll
    for (int qk = 0; qk < 2; ++qk) {
        const float (*P)[65] = qk ? pk : pq;
        float a1 = P[row_l][l15],      b1 = P[row_l][l15 + 32];
        float a2 = P[row_l][l15 + 16], b2 = P[row_l][l15 + 48];
        float o0 = a1 * c1 - b1 * s1;
        float o1 = a2 * c2 - b2 * s2;
        float o2 = a1 * s1 + b1 * c1;
        float o3 = a2 * s2 + b2 * c2;
        float loc = o0 * o0 + o1 * o1 + o2 * o2 + o3 * o3;
        #pragma unroll
        for (int xo = 1; xo < 16; xo <<= 1) loc += __shfl_xor(loc, xo, 64);
        float vn = sqrtf(loc);
        float scale, fn;
        if (vn < EPSF) { scale = 0.f; fn = 0.f; }
        else {
            float mag = tanh_fast(sqc * vn) / sqc;
            scale = mag / fmaxf(vn, EPSF);
            fn = mag;
            if (fn >= 1.f) { scale *= (1.f - EPSF) / fn; fn = 1.f - EPSF; }
        }
        unsigned short* outp = (qk ? kh : qh) + obase;
        outp[l15]      = f2bf(o0 * scale);
        outp[l15 + 16] = f2bf(o1 * scale);
        outp[l15 + 32] = f2bf(o2 * scale);
        outp[l15 + 48] = f2bf(o3 * scale);
        if (l15 == 0) (qk ? y2k : x2q)[h * N + n] = fn * fn;
    }
}

// K2: fused attention (R14 structure, R16 algebraic epilogue, R17: native
// base-2 HW exp/log: pe = 2^(alpha * log2((1-z)/(1+z))).
__global__ __launch_bounds__(256, 4) void k_attn(
        const unsigned short* __restrict__ qh, const unsigned short* __restrict__ kh,
        const unsigned short* __restrict__ vt,
        const float* __restrict__ x2q, const float* __restrict__ y2k,
        const float* __restrict__ c_logits, const float* __restrict__ geo_scale,
        unsigned short* __restrict__ aout) {
    const int N = 512;
    int rt = blockIdx.x, h = blockIdx.y;
    int r0 = rt * 16;
    int kend = r0 + 16;
    int tid = threadIdx.x;
    int wv = tid >> 6, lane = tid & 63, l15 = lane & 15, kb = lane >> 4;
    __shared__ __align__(16) unsigned short Ps[16][520];   // stride 1040B

    float c = softplus_fast(c_logits[h]);
    float sqc = fmaxf(sqrtf(c), EPSF);
    float gs = geo_scale[h];
    float alpha = gs / sqc;                 // pow exponent

    // ---- Phase 1: S tiles -> dist/exp -> LDS (zero-padded to even tiles) ----
    const unsigned short* qb = qh + ((size_t)h * N + r0 + l15) * 64 + kb * 8;
    s16x8 aq0 = *(const s16x8*)(qb);
    s16x8 aq1 = *(const s16x8*)(qb + 32);
    float x2v[4], bv[4];
    #pragma unroll
    for (int r = 0; r < 4; ++r) {
        int qi = r0 + kb * 4 + r;
        x2v[r] = x2q[h * N + qi];
        bv[r] = 1.f - c * x2v[r];
    }
    int ntile = rt + 1;
    int ntile_pad = (ntile + 1) & ~1;      // even # of 16-col tiles
    for (int j = wv; j < ntile_pad; j += 4) {
        if (j < ntile) {
            const unsigned short* kbp = kh + ((size_t)h * N + j * 16 + l15) * 64 + kb * 8;
            f32x4 s = {};
            s = __builtin_amdgcn_mfma_f32_16x16x32_bf16(aq0, *(const s16x8*)(kbp), s, 0, 0, 0);
            s = __builtin_amdgcn_mfma_f32_16x16x32_bf16(aq1, *(const s16x8*)(kbp + 32), s, 0, 0, 0);
            int ki = j * 16 + l15;
            float y2 = y2k[h * N + ki];
            #pragma unroll
            for (int r = 0; r < 4; ++r) {
                int qi = r0 + kb * 4 + r;
                float dot = s[r];
                float x2 = x2v[r], b_ = bv[r];
                float a_ = 1.f + c * (y2 - 2.f * dot);
                float num2 = a_ * a_ * x2 + b_ * b_ * y2 - 2.f * a_ * b_ * dot;
                float den = fmaxf(1.f - 2.f * c * dot + c * c * x2 * y2, EPSF);
                float nrm = sqrtf(fmaxf(num2, 0.f)) / den;
                if (nrm >= 1.f) nrm = 1.f - EPSF;
                float arg = fminf(sqc * nrm, 1.f - EPSF);
                float ratio = (1.f - arg) / (1.f + arg);
                float pe = exp2_hw(alpha * log2_hw(ratio));
                pe = (ki <= qi) ? pe : 0.f;
                Ps[kb * 4 + r][j * 16 + l15] = f2bf(pe);
            }
        } else {
            #pragma unroll
            for (int r = 0; r < 4; ++r)
                Ps[kb * 4 + r][j * 16 + l15] = 0;
        }
    }
    __syncthreads();

    // ---- Phase 2: O = P@V + ones-MFMA row-sum ----
    s16x8 ones;
    #pragma unroll
    for (int i = 0; i < 8; ++i) ones[i] = (short)0x3F80;   // bf16 1.0
    int d0 = wv * 16;
    const unsigned short* Vb = vt + ((size_t)(h * 64 + d0 + l15)) * N + kb * 8;
    f32x4 acc = {};
    f32x4 acc_s = {};
    for (int k0 = 0; k0 < kend; k0 += 32) {
        s16x8 a = *(const s16x8*)(&Ps[l15][k0 + kb * 8]);
        s16x8 b = *(const s16x8*)(Vb + k0);
        acc = __builtin_amdgcn_mfma_f32_16x16x32_bf16(a, b, acc, 0, 0, 0);
        acc_s = __builtin_amdgcn_mfma_f32_16x16x32_bf16(a, ones, acc_s, 0, 0, 0);
    }
    #pragma unroll
    for (int r = 0; r < 4; ++r) {
        int qi = r0 + kb * 4 + r;
        float il = 1.f / acc_s[r];
        aout[(size_t)qi * 512 + h * 64 + d0 + l15] = f2bf(acc[r] * il);
    }
}

// K3: out = aout(bf16) @ W_out + b. 16x16 tiles, W gathered fp32->bf16.
__global__ __launch_bounds__(256, 4) void k_out(
        const unsigned short* __restrict__ A, const float* __restrict__ W,
        const float* __restrict__ bias, float* __restrict__ C) {
    const int K = 512, NN = 512;
    int tid = threadIdx.x;
    int wv = tid >> 6, lane = tid & 63, l15 = lane & 15, kb = lane >> 4;
    int wr = blockIdx.x / 8;
    int cg = blockIdx.x % 8;
    int col0 = cg * 64 + wv * 16;
    const unsigned short* Ab = A + (size_t)(wr * 16 + l15) * K + kb * 8;
    f32x4 acc = {};
    #pragma unroll 4
    for (int k0 = 0; k0 < K; k0 += 32) {
        s16x8 a = *(const s16x8*)(Ab + k0);
        s16x8 b;
        #pragma unroll
        for (int t = 0; t < 8; ++t)
            b[t] = (short)f2bf(W[(size_t)(k0 + kb * 8 + t) * NN + col0 + l15]);
        acc = __builtin_amdgcn_mfma_f32_16x16x32_bf16(a, b, acc, 0, 0, 0);
    }
    int col = col0 + l15;
    float bv = bias[col];
    #pragma unroll
    for (int r = 0; r < 4; ++r)
        C[(size_t)(wr * 16 + kb * 4 + r) * NN + col] = acc[r] + bv;
}

extern "C" void kernel_launch(void* const* d_in, const int* in_sizes, int n_in,
                              void* d_out, int out_size, void* d_ws, size_t ws_size,
                              hipStream_t stream) {
    const float* x_hyp     = (const float*)d_in[0];
    const float* freqs     = (const float*)d_in[1];
    const float* c_sphere  = (const float*)d_in[2];
    const float* w_qkv     = (const float*)d_in[3];
    const float* b_qkv     = (const float*)d_in[4];
    const float* w_out     = (const float*)d_in[5];
    const float* b_out     = (const float*)d_in[6];
    const float* c_logits  = (const float*)d_in[7];
    const float* geo_scale = (const float*)d_in[8];
    float* out = (float*)d_out;

    const int H = 8;
    char* base = (char*)d_ws;
    unsigned short* qh16   = (unsigned short*)base;    base += 512 * 1024;
    unsigned short* kh16   = (unsigned short*)base;    base += 512 * 1024;
    unsigned short* vt16   = (unsigned short*)base;    base += 512 * 1024;
    unsigned short* aout16 = (unsigned short*)base;    base += 512 * 1024;
    float*          x2q    = (float*)base;             base += 16 * 1024;
    float*          y2k    = (float*)base;             base += 16 * 1024;

    k_qkv_rope<<<256, 256, 0, stream>>>(x_hyp, w_qkv, b_qkv, c_sphere, freqs,
                                        c_logits, qh16, kh16, vt16, x2q, y2k);
    k_attn<<<dim3(32, H), 256, 0, stream>>>(qh16, kh16, vt16, x2q, y2k,
                                            c_logits, geo_scale, aout16);
    k_out<<<256, 256, 0, stream>>>(aout16, w_out, b_out, out);
}

// Round 19
// 37.581 us; speedup vs baseline: 1.3927x; 1.1032x over previous
//
#include <hip/hip_runtime.h>
#include <hip/hip_bf16.h>
#include <math.h>

#define EPSF 1e-7f

typedef __attribute__((ext_vector_type(4))) float f32x4;
typedef __attribute__((ext_vector_type(8))) short s16x8;

// f2bf via the intrinsic cast (RNE) — the compiler pattern-matches scalar
// casts and emits packed v_cvt_pk_bf16_f32 (2 cvt/instr). The previous
// 4-op bit-twiddle was opaque to that optimization (m240 / T12 evidence).
__device__ __forceinline__ unsigned short f2bf(float f) {
    __hip_bfloat16 h = __float2bfloat16(f);
    union { __hip_bfloat16 b; unsigned short u; } cv;
    cv.b = h;
    return cv.u;
}
__device__ __forceinline__ s16x8 cvt8(const float* p) {
    s16x8 r;
    #pragma unroll
    for (int i = 0; i < 8; ++i) r[i] = (short)f2bf(p[i]);
    return r;
}
// raw HW transcendentals (base-2: v_exp_f32 = 2^x, v_log_f32 = log2)
__device__ __forceinline__ float exp2_hw(float x) {
    return __builtin_amdgcn_exp2f(x);
}
__device__ __forceinline__ float log2_hw(float x) {
    return __builtin_amdgcn_logf(x);
}
#define LOG2E 1.44269504088896340736f
#define LN2   0.69314718055994530942f
__device__ __forceinline__ float softplus_fast(float x) {
    return LN2 * log2_hw(1.f + exp2_hw(LOG2E * x));
}
__device__ __forceinline__ float tanh_fast(float x) {
    float t = exp2_hw(2.f * LOG2E * fminf(x, 10.f));
    return (t - 1.f) / (t + 1.f);
}

// K1: fused logmap + QKV GEMM + RoPE + expmap0.
__global__ __launch_bounds__(256, 4) void k_qkv_rope(
        const float* __restrict__ x, const float* __restrict__ W,
        const float* __restrict__ bias, const float* __restrict__ c_sphere,
        const float* __restrict__ freqs, const float* __restrict__ c_logits,
        unsigned short* __restrict__ qh, unsigned short* __restrict__ kh,
        unsigned short* __restrict__ vt,
        float* __restrict__ x2q, float* __restrict__ y2k) {
    const int K = 512, NN = 1536, N = 512;
    int b = blockIdx.x;
    int rt = b >> 3, h = b & 7;
    int n0 = rt * 16;
    int tid = threadIdx.x;
    int wv = tid >> 6, lane = tid & 63, l15 = lane & 15, kb = lane >> 4;
    __shared__ float part[16][16];
    __shared__ float sL[16];
    __shared__ float pq[16][65];
    __shared__ float pk[16][65];

    {   // logmap prologue
        int row = tid >> 4, seg = tid & 15;
        const float* xr = x + (size_t)(n0 + row) * K + seg * 32;
        float ss = 0.f;
        #pragma unroll
        for (int i = 0; i < 8; ++i) {
            float4 v = *(const float4*)(xr + i * 4);
            ss += v.x * v.x + v.y * v.y + v.z * v.z + v.w * v.w;
        }
        part[row][seg] = ss;
    }
    __syncthreads();
    if (tid < 16) {
        float ss = 0.f;
        #pragma unroll
        for (int i = 0; i < 16; ++i) ss += part[tid][i];
        float c = c_sphere[0];
        float sqc = fmaxf(sqrtf(c), EPSF);
        float yn = sqrtf(ss);
        sL[tid] = (yn < EPSF) ? 0.f
                 : atanhf(fminf(yn, 1.f - EPSF)) / (sqc * fmaxf(yn, EPSF));
    }
    __syncthreads();

    int cq = h * 64 + wv * 16 + l15;
    const float* Ab = x + (size_t)(n0 + l15) * K + kb * 8;
    f32x4 accq = {}, acck = {}, accv = {};
    #pragma unroll 4
    for (int k0 = 0; k0 < K; k0 += 32) {
        s16x8 a = cvt8(Ab + k0);
        s16x8 bq, bk, bv;
        #pragma unroll
        for (int t = 0; t < 8; ++t) {
            const float* wp = W + (size_t)(k0 + kb * 8 + t) * NN + cq;
            bq[t] = (short)f2bf(wp[0]);
            bk[t] = (short)f2bf(wp[512]);
            bv[t] = (short)f2bf(wp[1024]);
        }
        accq = __builtin_amdgcn_mfma_f32_16x16x32_bf16(a, bq, accq, 0, 0, 0);
        acck = __builtin_amdgcn_mfma_f32_16x16x32_bf16(a, bk, acck, 0, 0, 0);
        accv = __builtin_amdgcn_mfma_f32_16x16x32_bf16(a, bv, accv, 0, 0, 0);
    }
    {
        float bq_ = bias[cq], bk_ = bias[512 + cq], bv_ = bias[1024 + cq];
        int d = wv * 16 + l15;
        #pragma unroll
        for (int r = 0; r < 4; ++r) {
            int row_l = kb * 4 + r;
            float sc = sL[row_l];
            pq[row_l][d] = accq[r] * sc + bq_;
            pk[row_l][d] = acck[r] * sc + bk_;
            float vval = accv[r] * sc + bv_;
            vt[((size_t)(h * 64 + d)) * N + n0 + row_l] = f2bf(vval);
        }
    }
    __syncthreads();

    // RoPE + expmap: 4 vectors per wave in parallel (16-lane groups).
    int row_l = wv * 4 + kb;
    int n = n0 + row_l;
    float c = softplus_fast(c_logits[h]);
    float sqc = fmaxf(sqrtf(c), EPSF);
    float f1 = freqs[n * 32 + l15];
    float f2 = freqs[n * 32 + l15 + 16];
    float c1 = __cosf(f1), s1 = __sinf(f1);
    float c2 = __cosf(f2), s2 = __sinf(f2);
    size_t obase = ((size_t)h * N + n) * 64;
    #pragma unroll
    for (int qk = 0; qk < 2; ++qk) {
        const float (*P)[65] = qk ? pk : pq;
        float a1 = P[row_l][l15],      b1 = P[row_l][l15 + 32];
        float a2 = P[row_l][l15 + 16], b2 = P[row_l][l15 + 48];
        float o0 = a1 * c1 - b1 * s1;
        float o1 = a2 * c2 - b2 * s2;
        float o2 = a1 * s1 + b1 * c1;
        float o3 = a2 * s2 + b2 * c2;
        float loc = o0 * o0 + o1 * o1 + o2 * o2 + o3 * o3;
        #pragma unroll
        for (int xo = 1; xo < 16; xo <<= 1) loc += __shfl_xor(loc, xo, 64);
        float vn = sqrtf(loc);
        float scale, fn;
        if (vn < EPSF) { scale = 0.f; fn = 0.f; }
        else {
            float mag = tanh_fast(sqc * vn) / sqc;
            scale = mag / fmaxf(vn, EPSF);
            fn = mag;
            if (fn >= 1.f) { scale *= (1.f - EPSF) / fn; fn = 1.f - EPSF; }
        }
        unsigned short* outp = (qk ? kh : qh) + obase;
        outp[l15]      = f2bf(o0 * scale);
        outp[l15 + 16] = f2bf(o1 * scale);
        outp[l15 + 32] = f2bf(o2 * scale);
        outp[l15 + 48] = f2bf(o3 * scale);
        if (l15 == 0) (qk ? y2k : x2q)[h * N + n] = fn * fn;
    }
}

// K2: fused attention (R14 structure, R16 algebraic epilogue, R18 HW exp/log).
__global__ __launch_bounds__(256, 4) void k_attn(
        const unsigned short* __restrict__ qh, const unsigned short* __restrict__ kh,
        const unsigned short* __restrict__ vt,
        const float* __restrict__ x2q, const float* __restrict__ y2k,
        const float* __restrict__ c_logits, const float* __restrict__ geo_scale,
        unsigned short* __restrict__ aout) {
    const int N = 512;
    int rt = blockIdx.x, h = blockIdx.y;
    int r0 = rt * 16;
    int kend = r0 + 16;
    int tid = threadIdx.x;
    int wv = tid >> 6, lane = tid & 63, l15 = lane & 15, kb = lane >> 4;
    __shared__ __align__(16) unsigned short Ps[16][520];   // stride 1040B

    float c = softplus_fast(c_logits[h]);
    float sqc = fmaxf(sqrtf(c), EPSF);
    float gs = geo_scale[h];
    float alpha = gs / sqc;

    // ---- Phase 1: S tiles -> dist/exp -> LDS (zero-padded to even tiles) ----
    const unsigned short* qb = qh + ((size_t)h * N + r0 + l15) * 64 + kb * 8;
    s16x8 aq0 = *(const s16x8*)(qb);
    s16x8 aq1 = *(const s16x8*)(qb + 32);
    float x2v[4], bv[4];
    #pragma unroll
    for (int r = 0; r < 4; ++r) {
        int qi = r0 + kb * 4 + r;
        x2v[r] = x2q[h * N + qi];
        bv[r] = 1.f - c * x2v[r];
    }
    int ntile = rt + 1;
    int ntile_pad = (ntile + 1) & ~1;
    for (int j = wv; j < ntile_pad; j += 4) {
        if (j < ntile) {
            const unsigned short* kbp = kh + ((size_t)h * N + j * 16 + l15) * 64 + kb * 8;
            f32x4 s = {};
            s = __builtin_amdgcn_mfma_f32_16x16x32_bf16(aq0, *(const s16x8*)(kbp), s, 0, 0, 0);
            s = __builtin_amdgcn_mfma_f32_16x16x32_bf16(aq1, *(const s16x8*)(kbp + 32), s, 0, 0, 0);
            int ki = j * 16 + l15;
            float y2 = y2k[h * N + ki];
            #pragma unroll
            for (int r = 0; r < 4; ++r) {
                int qi = r0 + kb * 4 + r;
                float dot = s[r];
                float x2 = x2v[r], b_ = bv[r];
                float a_ = 1.f + c * (y2 - 2.f * dot);
                float num2 = a_ * a_ * x2 + b_ * b_ * y2 - 2.f * a_ * b_ * dot;
                float den = fmaxf(1.f - 2.f * c * dot + c * c * x2 * y2, EPSF);
                float nrm = sqrtf(fmaxf(num2, 0.f)) / den;
                if (nrm >= 1.f) nrm = 1.f - EPSF;
                float arg = fminf(sqc * nrm, 1.f - EPSF);
                float ratio = (1.f - arg) / (1.f + arg);
                float pe = exp2_hw(alpha * log2_hw(ratio));
                pe = (ki <= qi) ? pe : 0.f;
                Ps[kb * 4 + r][j * 16 + l15] = f2bf(pe);
            }
        } else {
            #pragma unroll
            for (int r = 0; r < 4; ++r)
                Ps[kb * 4 + r][j * 16 + l15] = 0;
        }
    }
    __syncthreads();

    // ---- Phase 2: O = P@V + ones-MFMA row-sum ----
    s16x8 ones;
    #pragma unroll
    for (int i = 0; i < 8; ++i) ones[i] = (short)0x3F80;   // bf16 1.0
    int d0 = wv * 16;
    const unsigned short* Vb = vt + ((size_t)(h * 64 + d0 + l15)) * N + kb * 8;
    f32x4 acc = {};
    f32x4 acc_s = {};
    for (int k0 = 0; k0 < kend; k0 += 32) {
        s16x8 a = *(const s16x8*)(&Ps[l15][k0 + kb * 8]);
        s16x8 b = *(const s16x8*)(Vb + k0);
        acc = __builtin_amdgcn_mfma_f32_16x16x32_bf16(a, b, acc, 0, 0, 0);
        acc_s = __builtin_amdgcn_mfma_f32_16x16x32_bf16(a, ones, acc_s, 0, 0, 0);
    }
    #pragma unroll
    for (int r = 0; r < 4; ++r) {
        int qi = r0 + kb * 4 + r;
        float il = 1.f / acc_s[r];
        aout[(size_t)qi * 512 + h * 64 + d0 + l15] = f2bf(acc[r] * il);
    }
}

// K3: out = aout(bf16) @ W_out + b. 16x16 tiles, W gathered fp32->bf16.
__global__ __launch_bounds__(256, 4) void k_out(
        const unsigned short* __restrict__ A, const float* __restrict__ W,
        const float* __restrict__ bias, float* __restrict__ C) {
    const int K = 512, NN = 512;
    int tid = threadIdx.x;
    int wv = tid >> 6, lane = tid & 63, l15 = lane & 15, kb = lane >> 4;
    int wr = blockIdx.x / 8;
    int cg = blockIdx.x % 8;
    int col0 = cg * 64 + wv * 16;
    const unsigned short* Ab = A + (size_t)(wr * 16 + l15) * K + kb * 8;
    f32x4 acc = {};
    #pragma unroll 4
    for (int k0 = 0; k0 < K; k0 += 32) {
        s16x8 a = *(const s16x8*)(Ab + k0);
        s16x8 b;
        #pragma unroll
        for (int t = 0; t < 8; ++t)
            b[t] = (short)f2bf(W[(size_t)(k0 + kb * 8 + t) * NN + col0 + l15]);
        acc = __builtin_amdgcn_mfma_f32_16x16x32_bf16(a, b, acc, 0, 0, 0);
    }
    int col = col0 + l15;
    float bv = bias[col];
    #pragma unroll
    for (int r = 0; r < 4; ++r)
        C[(size_t)(wr * 16 + kb * 4 + r) * NN + col] = acc[r] + bv;
}

extern "C" void kernel_launch(void* const* d_in, const int* in_sizes, int n_in,
                              void* d_out, int out_size, void* d_ws, size_t ws_size,
                              hipStream_t stream) {
    const float* x_hyp     = (const float*)d_in[0];
    const float* freqs     = (const float*)d_in[1];
    const float* c_sphere  = (const float*)d_in[2];
    const float* w_qkv     = (const float*)d_in[3];
    const float* b_qkv     = (const float*)d_in[4];
    const float* w_out     = (const float*)d_in[5];
    const float* b_out     = (const float*)d_in[6];
    const float* c_logits  = (const float*)d_in[7];
    const float* geo_scale = (const float*)d_in[8];
    float* out = (float*)d_out;

    const int H = 8;
    char* base = (char*)d_ws;
    unsigned short* qh16   = (unsigned short*)base;    base += 512 * 1024;
    unsigned short* kh16   = (unsigned short*)base;    base += 512 * 1024;
    unsigned short* vt16   = (unsigned short*)base;    base += 512 * 1024;
    unsigned short* aout16 = (unsigned short*)base;    base += 512 * 1024;
    float*          x2q    = (float*)base;             base += 16 * 1024;
    float*          y2k    = (float*)base;             base += 16 * 1024;

    k_qkv_rope<<<256, 256, 0, stream>>>(x_hyp, w_qkv, b_qkv, c_sphere, freqs,
                                        c_logits, qh16, kh16, vt16, x2q, y2k);
    k_attn<<<dim3(32, H), 256, 0, stream>>>(qh16, kh16, vt16, x2q, y2k,
                                            c_logits, geo_scale, aout16);
    k_out<<<256, 256, 0, stream>>>(aout16, w_out, b_out, out);
}